// Round 7
// baseline (108.621 us; speedup 1.0000x reference)
//
#include <hip/hip_runtime.h>

#define FEAT_DIM 256
#define K_NEIGH  32
#define NROWS    20480   // B*S = 2048*10
#define NOUT     1024    // CLIPS*DIM = 8*128
#define NUM_NODES 50000
#define SLICE_DIM 32     // dims per slice -> 3.2 MB/slice, fits 4 MB XCD L2
#define NSLICE    8
#define FBLK      1563   // ceil(NUM_NODES/32) feature blocks in cvt
#define NCHUNK    320    // row-chunks per slice (64 rows each)

typedef __attribute__((ext_vector_type(8))) short bf16x8;
typedef __attribute__((ext_vector_type(4))) float f32x4;

__device__ __forceinline__ unsigned short f2bf(float f) {
    unsigned int u = __builtin_bit_cast(unsigned int, f);
    u += 0x7fffu + ((u >> 16) & 1u);
    return (unsigned short)(u >> 16);
}
__device__ __forceinline__ float bf2f(unsigned short h) {
    unsigned int u = ((unsigned int)h) << 16;
    return __builtin_bit_cast(float, u);
}
__device__ __forceinline__ void gload16(const void* g, void* l) {
    __builtin_amdgcn_global_load_lds(
        (const __attribute__((address_space(1))) unsigned int*)g,
        (__attribute__((address_space(3))) unsigned int*)l, 16, 0, 0);
}

// ---- weight-only convert (fallback path) ------------------------------------
__global__ __launch_bounds__(256) void wcvt_kernel(const float* __restrict__ w,
                                                   unsigned short* __restrict__ wb) {
    int i = (blockIdx.x * 256 + threadIdx.x) * 4;
    float4 v = *(const float4*)(w + i);
    ushort4 o;
    o.x = f2bf(v.x); o.y = f2bf(v.y); o.z = f2bf(v.z); o.w = f2bf(v.w);
    *(ushort4*)(wb + i) = o;
}

// ---- convert: features -> fb[8][50000][32] bf16  +  W -> bf16  + ctr zero ---
__global__ __launch_bounds__(256) void cvt_kernel(const float* __restrict__ f,
                                                  unsigned short* __restrict__ fb,
                                                  const float* __restrict__ w,
                                                  unsigned short* __restrict__ wb,
                                                  int* __restrict__ ctr) {
    int b = blockIdx.x;
    int t = threadIdx.x;
    if (b < FBLK) {
        int g = t >> 5;            // slice 0..7
        int i = t & 31;            // node offset
        int node = b * 32 + i;
        if (node >= NUM_NODES) return;
        const float* src = f + (long)node * FEAT_DIM + g * SLICE_DIM;   // 128B/thr, block-dense
        unsigned short o[32];
        #pragma unroll
        for (int j = 0; j < 32; j += 4) {
            float4 v = *(const float4*)(src + j);
            o[j] = f2bf(v.x); o[j+1] = f2bf(v.y); o[j+2] = f2bf(v.z); o[j+3] = f2bf(v.w);
        }
        unsigned short* dst = fb + ((long)g * NUM_NODES + node) * SLICE_DIM; // 64B/thr contiguous
        #pragma unroll
        for (int j = 0; j < 4; ++j)
            *(bf16x8*)(dst + j * 8) = *(const bf16x8*)(o + j * 8);
    } else {
        if (b == FBLK && t < NSLICE) ctr[t] = 0;   // zero work-queue counters each launch
        int i = ((b - FBLK) * 256 + t) * 4;
        float4 v = *(const float4*)(w + i);
        ushort4 o;
        o.x = f2bf(v.x); o.y = f2bf(v.y); o.z = f2bf(v.z); o.w = f2bf(v.w);
        *(ushort4*)(wb + i) = o;
    }
}

// ---- agg: physically-XCD-pinned slices via HW_REG_XCC_ID + work stealing ----
// Each block reads its real XCD id, grabs a chunk of its own slice (local-L2
// gathers); steals from other slices only when its own is exhausted.
__global__ __launch_bounds__(256) void agg_xcc(const int* __restrict__ nodes,
                                               const int* __restrict__ adj,
                                               const unsigned short* __restrict__ fb,
                                               unsigned short* __restrict__ feat,
                                               int* __restrict__ ctr) {
    __shared__ int sslice, schunk;
    if (threadIdx.x == 0) {
        int xcc;
        asm volatile("s_getreg_b32 %0, hwreg(HW_REG_XCC_ID)" : "=s"(xcc));
        xcc &= 7;
        int slice = xcc;
        int chunk = atomicAdd(&ctr[slice], 1);      // device-scope by default
        #pragma unroll 1
        for (int o = 1; o < 8 && chunk >= NCHUNK; ++o) {
            slice = (xcc + o) & 7;
            chunk = atomicAdd(&ctr[slice], 1);
        }
        sslice = slice;
        schunk = chunk;
    }
    __syncthreads();
    int slice = sslice, chunk = schunk;
    if (chunk >= NCHUNK) return;                    // all work claimed

    int t = threadIdx.x;
    int row = chunk * 64 + (t >> 2);
    int d8 = (t & 3) * 8;
    int node = nodes[row];
    const int* arow = adj + (long)node * K_NEIGH;
    int nbr[K_NEIGH];
    #pragma unroll
    for (int kk = 0; kk < K_NEIGH / 4; ++kk)
        *(int4*)(nbr + kk * 4) = ((const int4*)arow)[kk];   // same-addr dedup in wave

    const unsigned short* base = fb + (long)slice * NUM_NODES * SLICE_DIM + d8;
    float acc[8] = {};
    #pragma unroll
    for (int k = 0; k < K_NEIGH; ++k) {
        bf16x8 v = *(const bf16x8*)(base + (long)nbr[k] * SLICE_DIM);  // local-L2 hit
        #pragma unroll
        for (int j = 0; j < 8; ++j) acc[j] += bf2f((unsigned short)v[j]);
    }
    unsigned short o[8];
    #pragma unroll
    for (int j = 0; j < 8; ++j) o[j] = f2bf(acc[j] * (1.0f / K_NEIGH));
    *(bf16x8*)(feat + (long)row * FEAT_DIM + slice * SLICE_DIM + d8) = *(const bf16x8*)o;
}

// ---- agg from fp32 features (ws fallback) -----------------------------------
__global__ __launch_bounds__(256) void agg_f32_kernel(const int* __restrict__ nodes,
                                                      const int* __restrict__ adj,
                                                      const float* __restrict__ features,
                                                      unsigned short* __restrict__ feat) {
    int row = blockIdx.x;
    int t = threadIdx.x;
    int node = nodes[row];
    const int* arow = adj + (long)node * K_NEIGH;
    float acc = 0.f;
    #pragma unroll
    for (int k = 0; k < K_NEIGH; ++k) {
        long nb = arow[k];
        acc += features[nb * FEAT_DIM + t];
    }
    feat[(long)row * FEAT_DIM + t] = f2bf(acc * (1.0f / K_NEIGH));
}

// ---- GEMM: C = relu(feat x W^T), 128x128 tile, dbuf LDS (unchanged R6) ------
__global__ __launch_bounds__(256) void gemm_kernel(const unsigned short* __restrict__ A,
                                                   const unsigned short* __restrict__ Bw,
                                                   float* __restrict__ C) {
    __shared__ short As[2][128 * 32];
    __shared__ short Bs[2][128 * 32];

    int bid = blockIdx.x;
    int xcd = bid & 7;
    int i2 = bid >> 3;
    int mt = xcd * 20 + (i2 % 20);
    int nt = i2 / 20;

    int t = threadIdx.x;
    int wave = t >> 6, lane = t & 63;
    int wm = wave >> 1, wn = wave & 1;
    int m0 = mt * 128, n0 = nt * 128;
    int lr = lane & 15;
    int lk = (lane >> 4) * 8;

    int srow = t >> 2;
    int sseg = (t & 3) * 8;
    const short* Ag = (const short*)A + (long)(m0 + srow) * FEAT_DIM + sseg;
    const short* Bg = (const short*)Bw + (long)(n0 + srow) * FEAT_DIM + sseg;

    f32x4 acc[4][4] = {};

#define STAGE(bufi, kb) do {                                         \
    gload16(Ag + (kb), &As[bufi][t * 8]);                            \
    gload16(Ag + 64 * FEAT_DIM + (kb), &As[bufi][64 * 32 + t * 8]);  \
    gload16(Bg + (kb), &Bs[bufi][t * 8]);                            \
    gload16(Bg + 64 * FEAT_DIM + (kb), &Bs[bufi][64 * 32 + t * 8]);  \
} while (0)

    STAGE(0, 0);
    asm volatile("s_waitcnt vmcnt(0)" ::: "memory");
    __builtin_amdgcn_s_barrier();

    #pragma unroll
    for (int it = 0; it < 8; ++it) {
        int cur = it & 1;
        if (it < 7) STAGE(cur ^ 1, (it + 1) * 32);

        bf16x8 a[4], b[4];
        #pragma unroll
        for (int i = 0; i < 4; ++i)
            a[i] = *(const bf16x8*)(&As[cur][(wm * 64 + i * 16 + lr) * 32 + lk]);
        #pragma unroll
        for (int j = 0; j < 4; ++j)
            b[j] = *(const bf16x8*)(&Bs[cur][(wn * 64 + j * 16 + lr) * 32 + lk]);
        #pragma unroll
        for (int i = 0; i < 4; ++i)
            #pragma unroll
            for (int j = 0; j < 4; ++j)
                acc[i][j] = __builtin_amdgcn_mfma_f32_16x16x32_bf16(a[i], b[j], acc[i][j], 0, 0, 0);

        if (it < 7) {
            asm volatile("s_waitcnt vmcnt(0)" ::: "memory");
            __builtin_amdgcn_s_barrier();
        }
    }
#undef STAGE

    int crow0 = m0 + wm * 64 + (lane >> 4) * 4;
    int ccol0 = n0 + wn * 64 + lr;
    #pragma unroll
    for (int i = 0; i < 4; ++i)
        #pragma unroll
        for (int j = 0; j < 4; ++j)
            #pragma unroll
            for (int r = 0; r < 4; ++r) {
                float v = acc[i][j][r];
                __builtin_nontemporal_store(v > 0.f ? v : 0.f,
                    &C[(long)(crow0 + i * 16 + r) * NOUT + ccol0 + j * 16]);
            }
}

extern "C" void kernel_launch(void* const* d_in, const int* in_sizes, int n_in,
                              void* d_out, int out_size, void* d_ws, size_t ws_size,
                              hipStream_t stream) {
    const int*   nodes    = (const int*)d_in[0];
    const int*   adj      = (const int*)d_in[1];
    const float* features = (const float*)d_in[2];
    const float* lw       = (const float*)d_in[3];
    float*       out      = (float*)d_out;

    const size_t fbf_elems  = (size_t)NUM_NODES * FEAT_DIM;
    const size_t feat_elems = (size_t)NROWS * FEAT_DIM;
    const size_t need = (fbf_elems + feat_elems + (size_t)NOUT * FEAT_DIM) * 2 + 64;

    if (ws_size >= need) {
        unsigned short* fbf  = (unsigned short*)d_ws;
        unsigned short* feat = fbf + fbf_elems;
        unsigned short* wb   = feat + feat_elems;
        int*            ctr  = (int*)(wb + (size_t)NOUT * FEAT_DIM);

        cvt_kernel<<<FBLK + (NOUT * FEAT_DIM) / (256 * 4), 256, 0, stream>>>(features, fbf, lw, wb, ctr);
        agg_xcc<<<NSLICE * NCHUNK, 256, 0, stream>>>(nodes, adj, fbf, feat, ctr);
        gemm_kernel<<<1280, 256, 0, stream>>>(feat, wb, out);
    } else {
        unsigned short* feat = (unsigned short*)d_ws;
        unsigned short* wb   = feat + feat_elems;

        wcvt_kernel<<<(NOUT * FEAT_DIM) / (256 * 4), 256, 0, stream>>>(lw, wb);
        agg_f32_kernel<<<NROWS, 256, 0, stream>>>(nodes, adj, features, feat);
        gemm_kernel<<<1280, 256, 0, stream>>>(feat, wb, out);
    }
}